// Round 1
// baseline (419.420 us; speedup 1.0000x reference)
//
#include <hip/hip_runtime.h>
#include <hip/hip_bf16.h>
#include <stdint.h>

typedef unsigned short ushort_t;
typedef __attribute__((ext_vector_type(8))) short short8;
typedef __attribute__((ext_vector_type(4))) float floatx4;
typedef __attribute__((ext_vector_type(4))) unsigned short ushortx4;

#define N64 4194304LL   // 65536*64

__device__ __forceinline__ ushort_t f2bf(float f) {
    union { float f; unsigned int i; } v; v.f = f;
    unsigned int u = v.i;
    return (ushort_t)((u + 0x7fffu + ((u >> 16) & 1u)) >> 16);
}

// tanh(x) = 1 - 2/(1+e^{2x})
__device__ __forceinline__ float fast_tanh(float x) {
    float e = __expf(2.f * x);
    return 1.f - 2.f / (e + 1.f);
}

#define GLD16(gp, lp) __builtin_amdgcn_global_load_lds( \
    (const __attribute__((address_space(1))) unsigned int*)(gp), \
    (__attribute__((address_space(3))) unsigned int*)(lp), 16, 0, 0)

// XOR-swizzled staging (one GLD16 = 16 rows x 64B):
//   lane l -> global row (l>>2), k-chunk (l&3)^((l>>3)&3)   [quad-contiguous 64B]
//   LDS chunk l*16B; frag read (row=fr, kquad=q) at fr*32 + ((q^((fr>>1)&3))*8)
// -> coalesced global AND conflict-free LDS reads (verified pattern).

// ---------------- fused prep: x cvt + 6 transposes + emb cvt + enorm ----------------
__device__ __forceinline__ void tile_transpose(const float* __restrict__ src,
                                               ushort_t* __restrict__ dst,
                                               int K, int M, int bx, int by, int tid,
                                               ushort_t (*tile)[65]) {
    const int m0 = bx * 64, k0 = by * 64;
    const int tr = tid >> 6, tc = tid & 63;
#pragma unroll
    for (int i = 0; i < 16; i++) {
        int kk = i * 4 + tr;
        tile[kk][tc] = f2bf(src[(long)(k0 + kk) * M + m0 + tc]);
    }
    __syncthreads();
#pragma unroll
    for (int i = 0; i < 16; i++) {
        int mm = i * 4 + tr;
        dst[(long)(m0 + mm) * K + k0 + tc] = tile[tc][mm];
    }
}

__global__ void prep_kernel(const float* __restrict__ x, ushort_t* __restrict__ xb,
                            const float* __restrict__ vq_w1, ushort_t* __restrict__ w1t,
                            const float* __restrict__ vq_w2, ushort_t* __restrict__ w2t,
                            const float* __restrict__ te_w1, ushort_t* __restrict__ te1t,
                            const float* __restrict__ te_w2, ushort_t* __restrict__ te2t,
                            const float* __restrict__ mean_w, ushort_t* __restrict__ mwt,
                            const float* __restrict__ lv_w, ushort_t* __restrict__ lwt,
                            const float* __restrict__ emb, ushort_t* __restrict__ embb,
                            float* __restrict__ enormG) {
    __shared__ ushort_t tile[64][65];
    const int b = blockIdx.x, tid = threadIdx.x;
    if (b < 32768) {                       // x fp32 -> bf16
        long i = (long)b * 256 + tid;
        float4 v = ((const float4*)x)[i];
        ushortx4 o;
        o.x = f2bf(v.x); o.y = f2bf(v.y); o.z = f2bf(v.z); o.w = f2bf(v.w);
        ((ushortx4*)xb)[i] = o;
    } else if (b < 32896) { int l = b - 32768; tile_transpose(vq_w1, w1t, 512, 1024, l & 15, l >> 4, tid, tile); }
    else if (b < 32912)   { int l = b - 32896; tile_transpose(vq_w2, w2t, 1024, 64, 0, l, tid, tile); }
    else if (b < 32928)   { int l = b - 32912; tile_transpose(te_w1, te1t, 64, 1024, l, 0, tid, tile); }
    else if (b < 33184)   { int l = b - 32928; tile_transpose(te_w2, te2t, 1024, 1024, l & 15, l >> 4, tid, tile); }
    else if (b < 33200)   { int l = b - 33184; tile_transpose(mean_w, mwt, 1024, 64, 0, l, tid, tile); }
    else if (b < 33216)   { int l = b - 33200; tile_transpose(lv_w, lwt, 1024, 64, 0, l, tid, tile); }
    else if (b < 33248) {                  // emb fp32 -> bf16
        int i = (b - 33216) * 256 + tid;
        float4 v = ((const float4*)emb)[i];
        ushortx4 o;
        o.x = f2bf(v.x); o.y = f2bf(v.y); o.z = f2bf(v.z); o.w = f2bf(v.w);
        ((ushortx4*)embb)[i] = o;
    } else {                               // codebook squared norms
        int c = (b - 33248) * 256 + tid;
        const float4* e = (const float4*)(emb + c * 64);
        float s = 0.f;
#pragma unroll
        for (int k = 0; k < 16; k++) { float4 v = e[k]; s += v.x * v.x + v.y * v.y + v.z * v.z + v.w * v.w; }
        enormG[c] = s;
    }
}

// ---------------- bf16 GEMM: C = act(A @ Bt^T + bias) (te1/te2 table GEMMs) ----------------
__global__ __launch_bounds__(256, 2) void gemm_bt_kernel(
    const ushort_t* __restrict__ A, const ushort_t* __restrict__ Bt,
    const float* __restrict__ bias, ushort_t* __restrict__ C,
    int K, int M, int do_tanh, int swizzled) {
    __shared__ ushort_t As[128 * 32];
    __shared__ ushort_t Bs[128 * 32];
    const int tid = threadIdx.x, wave = tid >> 6, lane = tid & 63;
    long row0, col0;
    if (swizzled) {
        const int bid = blockIdx.x;
        const int xcd = bid & 7, k = bid >> 3;
        row0 = (long)((k >> 3) * 8 + xcd) * 128;
        col0 = (long)(k & 7) * 128;
    } else {
        row0 = (long)blockIdx.y * 128;
        col0 = (long)blockIdx.x * 128;
    }
    const int fr = lane & 15, q = lane >> 4;
    const int srow = wave * 16 + (lane >> 2);
    const int skoff = ((lane & 3) ^ ((lane >> 3) & 3)) * 8;
    const ushort_t* aG = A + (row0 + srow) * K + skoff;
    const ushort_t* bG = Bt + (col0 + srow) * K + skoff;
    ushort_t* asW = As + wave * 512;
    ushort_t* bsW = Bs + wave * 512;
    floatx4 acc[4][4];
#pragma unroll
    for (int i = 0; i < 4; i++)
#pragma unroll
        for (int j = 0; j < 4; j++) acc[i][j] = (floatx4){0.f, 0.f, 0.f, 0.f};
    const int wm = (wave & 1) * 64, wn = (wave >> 1) * 64;
    const int ga = (wave & 1) * 4, gb = (wave >> 1) * 4;
    const int fidx = fr * 32 + ((q ^ ((fr >> 1) & 3)) << 3);
    for (int k0 = 0; k0 < K; k0 += 32) {
        GLD16(aG, asW);
        GLD16(aG + (long)64 * K, asW + 2048);
        GLD16(bG, bsW);
        GLD16(bG + (long)64 * K, bsW + 2048);
        aG += 32; bG += 32;
        __syncthreads();
        short8 af[4], bf[4];
#pragma unroll
        for (int i = 0; i < 4; i++) af[i] = *(const short8*)&As[(ga + i) * 512 + fidx];
#pragma unroll
        for (int j = 0; j < 4; j++) bf[j] = *(const short8*)&Bs[(gb + j) * 512 + fidx];
#pragma unroll
        for (int i = 0; i < 4; i++)
#pragma unroll
            for (int j = 0; j < 4; j++)
                acc[i][j] = __builtin_amdgcn_mfma_f32_16x16x32_bf16(af[i], bf[j], acc[i][j], 0, 0, 0);
        __syncthreads();
    }
    float bj[4];
#pragma unroll
    for (int j = 0; j < 4; j++) bj[j] = bias[col0 + wn + j * 16 + fr];
#pragma unroll
    for (int i = 0; i < 4; i++) {
        const long rb = row0 + wm + i * 16 + q * 4;
#pragma unroll
        for (int r = 0; r < 4; r++) {
            ushort_t* crow = C + (rb + r) * M + col0 + wn + fr;
#pragma unroll
            for (int j = 0; j < 4; j++) {
                float v = acc[i][j][r] + bj[j];
                if (do_tanh) v = fast_tanh(v);
                crow[j * 16] = f2bf(v);
            }
        }
    }
}

// ---------------- heads table: mean & log_var over 512 rows, fp32 tables out ----------------
__global__ __launch_bounds__(256, 2) void heads_tab_kernel(
    const ushort_t* __restrict__ A, const ushort_t* __restrict__ Mwt,
    const ushort_t* __restrict__ Lwt, const float* __restrict__ mb,
    const float* __restrict__ lb, float* __restrict__ meanTab,
    float* __restrict__ lvTab) {
    const int K = 1024;
    __shared__ ushort_t As[128 * 32];
    __shared__ ushort_t Bs[128 * 32];
    const int tid = threadIdx.x, wave = tid >> 6, lane = tid & 63;
    const long row0 = (long)blockIdx.x * 128;
    const int fr = lane & 15, q = lane >> 4;
    const int srow = wave * 16 + (lane >> 2);
    const int skoff = ((lane & 3) ^ ((lane >> 3) & 3)) * 8;
    const ushort_t* aG = A + (row0 + srow) * K + skoff;
    const ushort_t* bG0 = Mwt + (long)srow * K + skoff;
    const ushort_t* bG1 = Lwt + (long)srow * K + skoff;
    ushort_t* asW = As + wave * 512;
    ushort_t* bsW = Bs + wave * 512;
    floatx4 acc[4][4];
#pragma unroll
    for (int i = 0; i < 4; i++)
#pragma unroll
        for (int j = 0; j < 4; j++) acc[i][j] = (floatx4){0.f, 0.f, 0.f, 0.f};
    const int wm = (wave & 1) * 64, wn = (wave >> 1) * 64;
    const int ga = (wave & 1) * 4, gb = (wave >> 1) * 4;
    const int fidx = fr * 32 + ((q ^ ((fr >> 1) & 3)) << 3);
    for (int k0 = 0; k0 < K; k0 += 32) {
        GLD16(aG, asW);
        GLD16(aG + (long)64 * K, asW + 2048);
        GLD16(bG0, bsW);
        GLD16(bG1, bsW + 2048);
        aG += 32; bG0 += 32; bG1 += 32;
        __syncthreads();
        short8 af[4], bf[4];
#pragma unroll
        for (int i = 0; i < 4; i++) af[i] = *(const short8*)&As[(ga + i) * 512 + fidx];
#pragma unroll
        for (int j = 0; j < 4; j++) bf[j] = *(const short8*)&Bs[(gb + j) * 512 + fidx];
#pragma unroll
        for (int i = 0; i < 4; i++)
#pragma unroll
            for (int j = 0; j < 4; j++)
                acc[i][j] = __builtin_amdgcn_mfma_f32_16x16x32_bf16(af[i], bf[j], acc[i][j], 0, 0, 0);
        __syncthreads();
    }
    float bj[4];
    float* ob[4];
#pragma unroll
    for (int j = 0; j < 4; j++) {
        const int c = wn + j * 16 + fr;
        bj[j] = (c < 64) ? mb[c] : lb[c - 64];
        ob[j] = (c < 64) ? (meanTab + c) : (lvTab + (c - 64));
    }
#pragma unroll
    for (int i = 0; i < 4; i++) {
        const long rb = row0 + wm + i * 16 + q * 4;
#pragma unroll
        for (int r = 0; r < 4; r++) {
#pragma unroll
            for (int j = 0; j < 4; j++) ob[j][(rb + r) * 64] = acc[i][j][r] + bj[j];
        }
    }
}

// ---------------- FUSED: h=tanh(x@w1+b1) (per 128-col chunk, LDS-resident) ->
//                  z=h@w2+b2 (accumulated across chunks) -> argmin + idx + loss.
//                  h is never written to HBM. ----------------
#define HCS 136   // hc row stride (shorts): 272B = 68 banks -> 4-bank/row shift, 16B-aligned rows

__global__ __launch_bounds__(256, 2) void fused_enc_vq_kernel(
    const ushort_t* __restrict__ A,      // xb [65536,512] bf16
    const ushort_t* __restrict__ W1t,    // [1024,512] bf16
    const float* __restrict__ b1,
    const ushort_t* __restrict__ W2t,    // [64,1024] bf16
    const float* __restrict__ b2,
    const float* __restrict__ emb,
    const ushort_t* __restrict__ embb,
    const float* __restrict__ enormG,
    int* __restrict__ idxOut, float* __restrict__ lossAcc) {
    __shared__ ushort_t As[128 * 32];    // 8KB  x k-slab
    __shared__ ushort_t Bs[128 * 32];    // 8KB  w1 k-slab
    __shared__ ushort_t hc[128 * HCS];   // 34.8KB h-chunk bf16 (reused as zb at end)
    __shared__ ushort_t ws2[16 * 512];   // 16KB w2 chunk (reused as ebc at end)
    __shared__ int ridx[128];
    __shared__ float lred[4];
    const int tid = threadIdx.x, wave = tid >> 6, lane = tid & 63;
    const long row0 = (long)blockIdx.x * 128;
    const int fr = lane & 15, q = lane >> 4, kq = q * 8;
    const int srow = wave * 16 + (lane >> 2);
    const int skoff = ((lane & 3) ^ ((lane >> 3) & 3)) * 8;
    const int fidx = fr * 32 + ((q ^ ((fr >> 1) & 3)) << 3);
    const int er4 = lane >> 2;
    const int ec4 = (lane & 3) ^ ((lane >> 3) & 3);
    const int wm = (wave & 1) * 64, wn = (wave >> 1) * 64;
    const int ga = (wave & 1) * 4, gb = (wave >> 1) * 4;
    const int wr = wave * 32;
    ushort_t* asW = As + wave * 512;
    ushort_t* bsW = Bs + wave * 512;

    floatx4 accz[2][4];
#pragma unroll
    for (int i = 0; i < 2; i++)
#pragma unroll
        for (int j = 0; j < 4; j++) accz[i][j] = (floatx4){0.f, 0.f, 0.f, 0.f};

    for (int c = 0; c < 8; c++) {
        // stage w2t chunk: wave stages col-frag j==wave, 4 k-frags (16x32 units)
        {
            const ushort_t* wsrc = W2t + (wave * 16 + er4) * 1024 + c * 128 + ec4 * 8;
            ushort_t* wdst = ws2 + wave * 4 * 512;
            GLD16(wsrc,      wdst);
            GLD16(wsrc + 32, wdst + 512);
            GLD16(wsrc + 64, wdst + 1024);
            GLD16(wsrc + 96, wdst + 1536);
        }
        floatx4 acch[4][4];
#pragma unroll
        for (int i = 0; i < 4; i++)
#pragma unroll
            for (int j = 0; j < 4; j++) acch[i][j] = (floatx4){0.f, 0.f, 0.f, 0.f};
        const ushort_t* aG = A + (row0 + srow) * 512 + skoff;
        const ushort_t* bG = W1t + (long)(c * 128 + srow) * 512 + skoff;
        for (int k0 = 0; k0 < 512; k0 += 32) {
            GLD16(aG, asW);
            GLD16(aG + 64 * 512, asW + 2048);
            GLD16(bG, bsW);
            GLD16(bG + 64 * 512, bsW + 2048);
            aG += 32; bG += 32;
            __syncthreads();
            short8 af[4], bf[4];
#pragma unroll
            for (int i = 0; i < 4; i++) af[i] = *(const short8*)&As[(ga + i) * 512 + fidx];
#pragma unroll
            for (int j = 0; j < 4; j++) bf[j] = *(const short8*)&Bs[(gb + j) * 512 + fidx];
#pragma unroll
            for (int i = 0; i < 4; i++)
#pragma unroll
                for (int j = 0; j < 4; j++)
                    acch[i][j] = __builtin_amdgcn_mfma_f32_16x16x32_bf16(af[i], bf[j], acch[i][j], 0, 0, 0);
            __syncthreads();
        }
        // h-chunk epilogue: bias + tanh + bf16 into LDS (stride-HCS pad, 2-way-free banks)
#pragma unroll
        for (int j = 0; j < 4; j++) {
            const float bb = b1[c * 128 + wn + j * 16 + fr];
#pragma unroll
            for (int i = 0; i < 4; i++) {
                const int rb = wm + i * 16 + q * 4;
#pragma unroll
                for (int r = 0; r < 4; r++)
                    hc[(rb + r) * HCS + wn + j * 16 + fr] = f2bf(fast_tanh(acch[i][j][r] + bb));
            }
        }
        __syncthreads();   // hc ready (w2 chunk drained long ago by k-loop barriers)
        // z += hc @ w2chunk^T  (each wave: its 32 rows x all 64 z-cols)
#pragma unroll
        for (int ks = 0; ks < 4; ks++) {
            short8 a0 = *(const short8*)&hc[(wr + fr) * HCS + ks * 32 + kq];
            short8 a1 = *(const short8*)&hc[(wr + 16 + fr) * HCS + ks * 32 + kq];
#pragma unroll
            for (int j = 0; j < 4; j++) {
                short8 bw = *(const short8*)&ws2[(j * 4 + ks) * 512 + fidx];
                accz[0][j] = __builtin_amdgcn_mfma_f32_16x16x32_bf16(a0, bw, accz[0][j], 0, 0, 0);
                accz[1][j] = __builtin_amdgcn_mfma_f32_16x16x32_bf16(a1, bw, accz[1][j], 0, 0, 0);
            }
        }
        __syncthreads();   // ws2/hc reads done before next chunk's staging
    }
    // ---- bias, stage z (bf16) in A-operand layout (reuse hc) ----
#pragma unroll
    for (int j = 0; j < 4; j++) {
        const float bb = b2[j * 16 + fr];
#pragma unroll
        for (int i = 0; i < 2; i++)
#pragma unroll
            for (int r = 0; r < 4; r++) {
                accz[i][j][r] += bb;
                hc[(wr + i * 16 + q * 4 + r) * HCS + j * 16 + fr] = f2bf(accz[i][j][r]);
            }
    }
    __syncthreads();
    short8 za[2][2];
#pragma unroll
    for (int i = 0; i < 2; i++)
#pragma unroll
        for (int h = 0; h < 2; h++)
            za[i][h] = *(const short8*)&hc[(wr + i * 16 + fr) * HCS + h * 32 + kq];
    float minv[8]; int mini[8];
#pragma unroll
    for (int t = 0; t < 8; t++) { minv[t] = 3.0e38f; mini[t] = 0; }
    // ---- dist = ||e||^2 - 2 z.e, chunks of 128 codes (ebc = ws2 reuse) ----
    for (int ch = 0; ch < 4; ch++) {
        __syncthreads();   // previous chunk's MFMAs done before restage
        const ushort_t* esrc = embb + (long)(ch * 128) * 64;
        const int g0 = wave * 2;
        GLD16(esrc + (g0 * 16 + er4) * 64 + ec4 * 8,            ws2 + (g0 * 2 + 0) * 512);
        GLD16(esrc + (g0 * 16 + er4) * 64 + 32 + ec4 * 8,       ws2 + (g0 * 2 + 1) * 512);
        GLD16(esrc + ((g0 + 1) * 16 + er4) * 64 + ec4 * 8,      ws2 + (g0 * 2 + 2) * 512);
        GLD16(esrc + ((g0 + 1) * 16 + er4) * 64 + 32 + ec4 * 8, ws2 + (g0 * 2 + 3) * 512);
        __syncthreads();
#pragma unroll
        for (int jt = 0; jt < 8; jt++) {
            const int code = ch * 128 + jt * 16 + fr;
            short8 e0 = *(const short8*)&ws2[(jt * 2 + 0) * 512 + fidx];
            short8 e1 = *(const short8*)&ws2[(jt * 2 + 1) * 512 + fidx];
            float en = enormG[code];
#pragma unroll
            for (int i = 0; i < 2; i++) {
                floatx4 s = (floatx4){0.f, 0.f, 0.f, 0.f};
                s = __builtin_amdgcn_mfma_f32_16x16x32_bf16(za[i][0], e0, s, 0, 0, 0);
                s = __builtin_amdgcn_mfma_f32_16x16x32_bf16(za[i][1], e1, s, 0, 0, 0);
#pragma unroll
                for (int r = 0; r < 4; r++) {
                    float d = en - 2.f * s[r];
                    int t = i * 4 + r;
                    if (d < minv[t]) { minv[t] = d; mini[t] = code; }
                }
            }
        }
    }
    // argmin across the 16 lanes sharing each output row
#pragma unroll
    for (int m = 1; m < 16; m <<= 1) {
#pragma unroll
        for (int t = 0; t < 8; t++) {
            float ov = __shfl_xor(minv[t], m, 64);
            int oi = __shfl_xor(mini[t], m, 64);
            if (ov < minv[t] || (ov == minv[t] && oi < mini[t])) { minv[t] = ov; mini[t] = oi; }
        }
    }
    if (fr == 0) {
#pragma unroll
        for (int t = 0; t < 8; t++) {
            int row = wr + (t >> 2) * 16 + q * 4 + (t & 3);
            ridx[row] = mini[t];
            idxOut[row0 + row] = mini[t];
        }
    }
    __syncthreads();
    // ---- loss partial: sum (z_q - z)^2, fp32 ----
    float s = 0.f;
#pragma unroll
    for (int i = 0; i < 2; i++)
#pragma unroll
        for (int r = 0; r < 4; r++) {
            int row = wr + i * 16 + q * 4 + r;
            int idx = ridx[row];
#pragma unroll
            for (int j = 0; j < 4; j++) {
                int col = j * 16 + fr;
                float zq = emb[idx * 64 + col];
                float d = zq - accz[i][j][r];
                s += d * d;
            }
        }
#pragma unroll
    for (int m = 1; m < 64; m <<= 1) s += __shfl_xor(s, m, 64);
    if (lane == 0) lred[wave] = s;
    __syncthreads();
    if (tid == 0) atomicAdd(lossAcc, lred[0] + lred[1] + lred[2] + lred[3]);
}

// ---------------- gather: out rows from 512-entry tables ----------------
__global__ void gather_out_kernel(const int* __restrict__ idx,
                                  const float4* __restrict__ meanTab,
                                  const float4* __restrict__ lvTab,
                                  float4* __restrict__ out) {
    int g = blockIdx.x * 256 + threadIdx.x;
    int row = g >> 4, part = g & 15;
    int id = idx[row];
    out[g] = meanTab[id * 16 + part];
    out[1048576 + g] = lvTab[id * 16 + part];
}

__global__ void finish_kernel(const float* __restrict__ lossAcc, float* __restrict__ out) {
    out[0] = lossAcc[0] * (1.f / (65536.f * 32.f));   // 2*sum/(N*64)
}

extern "C" void kernel_launch(void* const* d_in, const int* in_sizes, int n_in,
                              void* d_out, int out_size, void* d_ws, size_t ws_size,
                              hipStream_t stream) {
    const float* x      = (const float*)d_in[0];
    const float* vq_w1  = (const float*)d_in[1];
    const float* vq_b1  = (const float*)d_in[2];
    const float* vq_w2  = (const float*)d_in[3];
    const float* vq_b2  = (const float*)d_in[4];
    const float* emb    = (const float*)d_in[5];
    const float* te_w1  = (const float*)d_in[6];
    const float* te_b1  = (const float*)d_in[7];
    const float* te_w2  = (const float*)d_in[8];
    const float* te_b2  = (const float*)d_in[9];
    const float* mean_w = (const float*)d_in[10];
    const float* mean_b = (const float*)d_in[11];
    const float* lv_w   = (const float*)d_in[12];
    const float* lv_b   = (const float*)d_in[13];
    float* out = (float*)d_out;
    char* ws = (char*)d_ws;
    ushort_t* xb      = (ushort_t*)(ws + 0LL);          // 64MB  [65536,512] bf16
    // (h buffer at +67108864 no longer used — h never materialized)
    ushort_t* w1t     = (ushort_t*)(ws + 201326592LL);  // 1MB   [1024,512]
    ushort_t* te2t    = (ushort_t*)(ws + 202375168LL);  // 2MB   [1024,1024]
    ushort_t* w2t     = (ushort_t*)(ws + 204472320LL);  // 128KB [64,1024]
    ushort_t* te1t    = (ushort_t*)(ws + 204603392LL);  // 128KB [1024,64]
    ushort_t* mwt     = (ushort_t*)(ws + 204734464LL);  // 128KB [64,1024]
    ushort_t* lwt     = (ushort_t*)(ws + 204865536LL);  // 128KB [64,1024]
    ushort_t* embb    = (ushort_t*)(ws + 204996608LL);  // 64KB  [512,64] bf16
    ushort_t* t1tab   = (ushort_t*)(ws + 205062144LL);  // 1MB   [512,1024] bf16
    ushort_t* t2tab   = (ushort_t*)(ws + 206110720LL);  // 1MB   [512,1024] bf16
    float*    meanTab = (float*)   (ws + 207159296LL);  // 128KB [512,64] fp32
    float*    lvTab   = (float*)   (ws + 207290368LL);  // 128KB [512,64] fp32
    int*      idxbuf  = (int*)     (ws + 207421440LL);  // 256KB [65536] int32
    float*    enormG  = (float*)   (ws + 207683584LL);  // 2KB   [512] fp32
    float*    lossAcc = (float*)   (ws + 207685632LL);  // 4B

    hipMemsetAsync(lossAcc, 0, 4, stream);
    prep_kernel<<<33250, 256, 0, stream>>>(x, xb, vq_w1, w1t, vq_w2, w2t, te_w1, te1t,
                                           te_w2, te2t, mean_w, mwt, lv_w, lwt,
                                           emb, embb, enormG);
    // fused encoder + VQ: h stays on-chip; 512 blocks = exactly 2/CU on 256 CUs
    fused_enc_vq_kernel<<<512, 256, 0, stream>>>(xb, w1t, vq_b1, w2t, vq_b2,
                                                 emb, embb, enormG, idxbuf, lossAcc);
    // codebook-table pipeline (512 rows only)
    gemm_bt_kernel<<<dim3(8, 4), 256, 0, stream>>>(embb, te1t, te_b1, t1tab, 64, 1024, 1, 0);
    gemm_bt_kernel<<<dim3(8, 4), 256, 0, stream>>>(t1tab, te2t, te_b2, t2tab, 1024, 1024, 1, 0);
    heads_tab_kernel<<<4, 256, 0, stream>>>(t2tab, mwt, lwt, mean_b, lv_b, meanTab, lvTab);
    gather_out_kernel<<<4096, 256, 0, stream>>>(idxbuf, (const float4*)meanTab,
                                                (const float4*)lvTab, (float4*)out);
    finish_kernel<<<1, 1, 0, stream>>>(lossAcc, out + 2 * N64);
}